// Round 7
// baseline (371.418 us; speedup 1.0000x reference)
//
#include <hip/hip_runtime.h>

// BSPLoss: out = sig1(f1)^2 + 0.5*(sig1(f2)^2 + sig1(f3)^2), f: 8192x1024 fp32.
// sig1^2 = top eig of G = f'f. bf16 MFMA for G and 5 trace-normalized squarings
// (eigenvector only); final lambda = (w' G32 w)/|w|^2 with fp32-accumulated Gram.
// R19: sq_k operand M is 2MB bf16 = L2-resident (4MB/XCD). LDS staging of
// L2-fit data is pure overhead (common-mistake #7). M symmetric => both sq
// fragments are row-major k-contig; staged+swizzled path provably reduces to
// lane l reading S[(rowbase+(l&15))*DIM + k0 + (l>>4)*8] -- so load fragments
// DIRECT from L2 into VGPRs. Zero K-loop barriers (compiler pipelines plain
// loads), LDS 41KB -> 8.7KB (Ts only). Bit-identical acc => absmax stays 256.
// syrk unchanged (R17's 2-phase, 54.4us) as control.

#define DIM 1024
#define NROW 8192
#define MSZ (DIM*DIM)
#define NS 5

typedef __attribute__((ext_vector_type(8))) short short8;
typedef __attribute__((ext_vector_type(4))) float f32x4;

__device__ inline float bf2f(unsigned short u) {
    union { unsigned i; float f; } x; x.i = ((unsigned)u) << 16; return x.f;
}
__device__ inline unsigned short f2bf(float f) {
    union { float f; unsigned i; } x; x.f = f;
    unsigned r = x.i + 0x7FFFu + ((x.i >> 16) & 1u);
    return (unsigned short)(r >> 16);
}
__device__ inline void gload16(const void* g, void* l) {
    __builtin_amdgcn_global_load_lds(
        (const __attribute__((address_space(1))) unsigned int*)g,
        (__attribute__((address_space(3))) unsigned int*)l, 16, 0, 0);
}

// f fp32 [NROW][DIM] -> ft bf16 [DIM][NROW] (transposed), per matrix m.
__global__ __launch_bounds__(256)
void tconv_k(const float* __restrict__ f0, const float* __restrict__ f1,
             const float* __restrict__ f2, unsigned short* __restrict__ ft) {
    const int m = blockIdx.z;
    const float* f = (m == 0) ? f0 : (m == 1 ? f1 : f2);
    unsigned short* o = ft + (size_t)m * DIM * NROW;
    __shared__ float T[64][68];
    const int c0 = blockIdx.x * 64, r0 = blockIdx.y * 64;
    const int tid = threadIdx.x;
    const int cx = (tid & 15) * 4, ry = tid >> 4;
#pragma unroll
    for (int i = 0; i < 4; ++i) {
        int r = ry + i * 16;
        float4 v = *(const float4*)&f[(size_t)(r0 + r) * DIM + c0 + cx];
        T[cx + 0][r] = v.x;
        T[cx + 1][r] = v.y;
        T[cx + 2][r] = v.z;
        T[cx + 3][r] = v.w;
    }
    __syncthreads();
#pragma unroll
    for (int i = 0; i < 4; ++i) {
        int c = ry + i * 16;
        float4 g = *(const float4*)&T[c][cx];
        ushort4 u;
        u.x = f2bf(g.x); u.y = f2bf(g.y); u.z = f2bf(g.z); u.w = f2bf(g.w);
        *(ushort4*)&o[(size_t)(c0 + c) * NROW + r0 + cx] = u;
    }
}

// Split-K(4) symmetric SYRK, upper 128-tiles, fp32 atomicAdd into packed G.
// Flat grid 432: b = ky + 4*(tile + 36*m). XCD = b%8 = ky + 4*(tile&1).
// 2-phase software pipeline: ping-pong LDS (As0/Bs0, As1/Bs1), prefetch of
// K-step t+1 issued before compute of t, one __syncthreads per K-step.
__global__ __launch_bounds__(256)
void syrk_sk(const unsigned short* __restrict__ src, float* __restrict__ Gp) {
    const int b = blockIdx.x;
    const int ky = b & 3;
    const int q = b >> 2;            // 0..107
    const int m = q / 36;
    const int tile = q - m * 36;
    int idx = tile, ti = 0;
    while (idx >= 8 - ti) { idx -= 8 - ti; ++ti; }
    const int tj = ti + idx;
    const int i0 = ti * 128, j0 = tj * 128;
    const unsigned short* S = src + (size_t)m * DIM * NROW;
    float* G = Gp + ((size_t)m * 36 + tile) * 16384;
    const int k0b = ky << 11;        // Kc = 2048, 32 K-steps of 64

    __shared__ unsigned short As0[2 * 128 * 32];   // 16 KB each
    __shared__ unsigned short Bs0[2 * 128 * 32];
    __shared__ unsigned short As1[2 * 128 * 32];
    __shared__ unsigned short Bs1[2 * 128 * 32];

    const int tid = threadIdx.x, w = tid >> 6, lane = tid & 63;
    const int wi = w >> 1, wj = w & 1;

    f32x4 acc[4][4];
#pragma unroll
    for (int a = 0; a < 4; ++a)
#pragma unroll
        for (int c = 0; c < 4; ++c) acc[a][c] = (f32x4){0.f, 0.f, 0.f, 0.f};

    const int lr = lane >> 2;
    const int ksw = (((lane & 3) ^ ((lane >> 4) & 3)) * 8);
    const int fr = lane & 15;
    const int slot = (((lane >> 4) ^ ((fr >> 2) & 3)) * 8);

#define STAGE(AS, BS, KK)                                                     \
    _Pragma("unroll")                                                         \
    for (int h = 0; h < 2; ++h)                                               \
        _Pragma("unroll")                                                     \
        for (int p = 0; p < 2; ++p) {                                         \
            int rr = w * 32 + p * 16;                                         \
            gload16(S + (size_t)(i0 + rr + lr) * NROW + (KK) + h * 32 + ksw,  \
                    &(AS)[h * 4096 + rr * 32]);                               \
            gload16(S + (size_t)(j0 + rr + lr) * NROW + (KK) + h * 32 + ksw,  \
                    &(BS)[h * 4096 + rr * 32]);                               \
        }

#define COMPUTE(AS, BS)                                                       \
    _Pragma("unroll")                                                         \
    for (int h = 0; h < 2; ++h) {                                             \
        short8 af[4], bfv[4];                                                 \
        _Pragma("unroll")                                                     \
        for (int a = 0; a < 4; ++a)                                           \
            af[a] = *(const short8*)&(AS)[h * 4096 + (wi * 64 + a * 16 + fr) * 32 + slot]; \
        _Pragma("unroll")                                                     \
        for (int c = 0; c < 4; ++c)                                           \
            bfv[c] = *(const short8*)&(BS)[h * 4096 + (wj * 64 + c * 16 + fr) * 32 + slot]; \
        _Pragma("unroll")                                                     \
        for (int a = 0; a < 4; ++a)                                           \
            _Pragma("unroll")                                                 \
            for (int c = 0; c < 4; ++c)                                       \
                acc[a][c] = __builtin_amdgcn_mfma_f32_16x16x32_bf16(          \
                    af[a], bfv[c], acc[a][c], 0, 0, 0);                       \
    }

    // Prologue: stage K-step 0 into buf0.
    STAGE(As0, Bs0, k0b)
    __syncthreads();

    int k0 = k0b;
#pragma unroll 1
    for (int t = 0; t < 15; ++t) {
        STAGE(As1, Bs1, k0 + 64)      // prefetch odd step
        COMPUTE(As0, Bs0)             // compute even step (latency hides here)
        __syncthreads();              // drains prefetch, guards buf reuse
        STAGE(As0, Bs0, k0 + 128)     // prefetch next even step
        COMPUTE(As1, Bs1)
        __syncthreads();
        k0 += 128;
    }
    // Tail: steps 30 (staged in last loop iter) and 31.
    STAGE(As1, Bs1, k0 + 64)
    COMPUTE(As0, Bs0)
    __syncthreads();
    COMPUTE(As1, Bs1)

#undef STAGE
#undef COMPUTE

    const int qr = (lane >> 4) * 4, cn = lane & 15;
#pragma unroll
    for (int a = 0; a < 4; ++a)
#pragma unroll
        for (int c = 0; c < 4; ++c) {
            int cl = wj * 64 + c * 16 + cn;
#pragma unroll
            for (int reg = 0; reg < 4; ++reg) {
                int rl = wi * 64 + a * 16 + qr + reg;
                atomicAdd(&G[rl * 128 + cl], acc[a][c][reg]);
            }
        }
}

// Packed-upper fp32 G -> full bf16 matrix (mirror via swizzled LDS transpose),
// fused trace -> trout[m]. grid (36,1,3). G32 read-only (kept for ray_k).
__global__ __launch_bounds__(256)
void convert_k(const float* __restrict__ Gp, float* __restrict__ trout,
               unsigned short* __restrict__ dst) {
    const int m = blockIdx.z;
    int idx = blockIdx.x, ti = 0;
    while (idx >= 8 - ti) { idx -= 8 - ti; ++ti; }
    const int tj = ti + idx;
    const int i0 = ti * 128, j0 = tj * 128;
    const float* G = Gp + ((size_t)m * 36 + blockIdx.x) * 16384;
    unsigned short* D = dst + (size_t)m * MSZ;
    __shared__ unsigned short T[128][136];
    const int tid = threadIdx.x;
    const int cx = (tid & 31) * 4, ry = tid >> 5;
    float dtr = 0.f;
#pragma unroll 4
    for (int t = 0; t < 16; ++t) {
        int r = ry + t * 8;
        float4 g = *(const float4*)&G[r * 128 + cx];
        ushort4 o;
        o.x = f2bf(g.x); o.y = f2bf(g.y); o.z = f2bf(g.z); o.w = f2bf(g.w);
        *(ushort4*)&D[(size_t)(i0 + r) * DIM + j0 + cx] = o;
        int rs = r ^ (cx & 124);
        T[cx + 0][rs] = o.x; T[cx + 1][rs] = o.y;
        T[cx + 2][rs] = o.z; T[cx + 3][rs] = o.w;
        if (ti == tj) {
            int d = r - cx;
            if (d >= 0 && d < 4)
                dtr += (d == 0 ? g.x : d == 1 ? g.y : d == 2 ? g.z : g.w);
        }
    }
    if (ti == tj) atomicAdd(&trout[m], dtr);
    if (ti != tj) {
        __syncthreads();
#pragma unroll 4
        for (int t = 0; t < 16; ++t) {
            int p = ry + t * 8;
            int qs = cx ^ (p & 124);
            ushort4 o = *(const ushort4*)&T[p][qs];
            *(ushort4*)&D[(size_t)(j0 + p) * DIM + i0 + cx] = o;
        }
    }
}

// One trace-normalized squaring: dst = (src/tr)^2, symmetric 64-tiles, fused
// scale + mirror + trace. grid (136,1,3). R19: M is L2-resident (2MB) and
// symmetric => fragments load DIRECT from global into VGPRs (bit-identical
// to the old staged path: lane l reads row (base+(l&15)), k-chunk (l>>4)*8).
// No LDS operand staging, no K-loop barriers; compiler pipelines the loads.
__global__ __launch_bounds__(256)
void sq_k(const unsigned short* __restrict__ src, const float* __restrict__ trin,
          float* __restrict__ trout, unsigned short* __restrict__ dst) {
    const int m = blockIdx.z;
    const unsigned short* S = src + (size_t)m * MSZ;
    unsigned short* D = dst + (size_t)m * MSZ;
    int idx = blockIdx.x, ti = 0;
    while (idx >= 16 - ti) { idx -= 16 - ti; ++ti; }
    const int tj = ti + idx;
    const int i0 = ti * 64, j0 = tj * 64;
    float tv = trin[m];
    const float sc = 1.f / (tv * tv);

    __shared__ unsigned short Ts[64][68];

    const int tid = threadIdx.x, w = tid >> 6, lane = tid & 63;
    const int wi = w >> 1, wj = w & 1;
    const int fr = lane & 15, kq = (lane >> 4) * 8;

    f32x4 acc[2][2];
#pragma unroll
    for (int a = 0; a < 2; ++a)
#pragma unroll
        for (int b = 0; b < 2; ++b) acc[a][b] = (f32x4){0.f, 0.f, 0.f, 0.f};

    // Per-lane fragment row pointers (k-contiguous; 16 lanes x 4 chunks of
    // 16B per fragment = 64B segments per row -> coalesced L2 reads).
    const unsigned short* A0 = S + (size_t)(i0 + wi * 32 + fr) * DIM + kq;
    const unsigned short* A1 = A0 + 16 * DIM;
    const unsigned short* B0 = S + (size_t)(j0 + wj * 32 + fr) * DIM + kq;
    const unsigned short* B1 = B0 + 16 * DIM;

#pragma unroll 4
    for (int k0 = 0; k0 < DIM; k0 += 32) {
        short8 a0 = *(const short8*)(A0 + k0);
        short8 a1 = *(const short8*)(A1 + k0);
        short8 b0 = *(const short8*)(B0 + k0);
        short8 b1 = *(const short8*)(B1 + k0);
        acc[0][0] = __builtin_amdgcn_mfma_f32_16x16x32_bf16(a0, b0, acc[0][0], 0, 0, 0);
        acc[0][1] = __builtin_amdgcn_mfma_f32_16x16x32_bf16(a0, b1, acc[0][1], 0, 0, 0);
        acc[1][0] = __builtin_amdgcn_mfma_f32_16x16x32_bf16(a1, b0, acc[1][0], 0, 0, 0);
        acc[1][1] = __builtin_amdgcn_mfma_f32_16x16x32_bf16(a1, b1, acc[1][1], 0, 0, 0);
    }

    const int qr = (lane >> 4) * 4, cn = lane & 15;
#pragma unroll
    for (int a = 0; a < 2; ++a)
#pragma unroll
        for (int b = 0; b < 2; ++b) {
            int cl = wj * 32 + b * 16 + cn;
#pragma unroll
            for (int reg = 0; reg < 4; ++reg) {
                int rl = wi * 32 + a * 16 + qr + reg;
                unsigned short val = f2bf(acc[a][b][reg] * sc);
                D[(size_t)(i0 + rl) * DIM + j0 + cl] = val;
                Ts[cl][rl] = val;
            }
        }
    if (ti == tj && wi == wj) {
        int d = cn - qr;
        if (d >= 0 && d < 4)
            atomicAdd(&trout[m], (acc[0][0][d] + acc[1][1][d]) * sc);
    }
    if (ti != tj) {
        __syncthreads();
        const int cx = (tid & 15) * 4, ry = tid >> 4;
#pragma unroll
        for (int tq = 0; tq < 4; ++tq) {
            int p = ry + tq * 16;
            ushort4 o;
            o.x = Ts[p][cx + 0]; o.y = Ts[p][cx + 1];
            o.z = Ts[p][cx + 2]; o.w = Ts[p][cx + 3];
            *(ushort4*)&D[(size_t)(j0 + p) * DIM + i0 + cx] = o;
        }
    }
}

// vout[row] = sum_j M[row][j] * (vin ? vin[j] : 1), M bf16 symmetric.
__global__ __launch_bounds__(256)
void mv_bf16(const unsigned short* __restrict__ M, const float* __restrict__ vin,
             float* __restrict__ vout) {
    int m = blockIdx.y;
    const unsigned short* A = M + (size_t)m * MSZ;
    int wv = threadIdx.x >> 6, lane = threadIdx.x & 63;
    int row = blockIdx.x * 4 + wv;
    const unsigned short* a = A + (size_t)row * DIM;
    float s = 0.f;
    if (vin) {
        const float* v = vin + m * DIM;
        for (int j = lane; j < DIM; j += 64) s += bf2f(a[j]) * v[j];
    } else {
        for (int j = lane; j < DIM; j += 64) s += bf2f(a[j]);
    }
    for (int off = 32; off; off >>= 1) s += __shfl_down(s, off);
    if (lane == 0) vout[m * DIM + row] = s;
}

// num[m] += w_i' T w_j (x2 off-diag) over packed-upper fp32 tiles. grid (36,3).
__global__ __launch_bounds__(256)
void ray_k(const float* __restrict__ Gp, const float* __restrict__ wv,
           float* __restrict__ num) {
    const int m = blockIdx.y;
    int idx = blockIdx.x, ti = 0;
    while (idx >= 8 - ti) { idx -= 8 - ti; ++ti; }
    const int tj = ti + idx;
    const float* G = Gp + ((size_t)m * 36 + blockIdx.x) * 16384;
    const float* wi = wv + m * DIM + ti * 128;
    const float* wj = wv + m * DIM + tj * 128;
    const int tid = threadIdx.x;
    const int r = tid >> 1, c0 = (tid & 1) * 64;
    float inner = 0.f;
    const float4* g4 = (const float4*)&G[r * 128 + c0];
    const float4* w4 = (const float4*)&wj[c0];
#pragma unroll
    for (int t = 0; t < 16; ++t) {
        float4 g = g4[t], ww = w4[t];
        inner += g.x * ww.x + g.y * ww.y + g.z * ww.z + g.w * ww.w;
    }
    float s = wi[r] * inner;
    for (int off = 32; off; off >>= 1) s += __shfl_down(s, off);
    __shared__ float part[4];
    int lane = tid & 63, wx = tid >> 6;
    if (lane == 0) part[wx] = s;
    __syncthreads();
    if (tid == 0) {
        float tot = part[0] + part[1] + part[2] + part[3];
        if (ti != tj) tot *= 2.f;
        atomicAdd(&num[m], tot);
    }
}

// out = num0/|w0|^2 + 0.5*(num1/|w1|^2 + num2/|w2|^2)
__global__ __launch_bounds__(256)
void final_k(const float* __restrict__ num, const float* __restrict__ w,
             float* __restrict__ out) {
    __shared__ float red[256];
    int tid = threadIdx.x;
    float lam[3];
    for (int m = 0; m < 3; ++m) {
        float s = 0.f;
        for (int i = tid; i < DIM; i += 256) { float x = w[m * DIM + i]; s += x * x; }
        red[tid] = s; __syncthreads();
        for (int off = 128; off; off >>= 1) {
            if (tid < off) red[tid] += red[tid + off];
            __syncthreads();
        }
        lam[m] = num[m] / red[0]; __syncthreads();
    }
    if (tid == 0) out[0] = lam[0] + 0.5f * (lam[1] + lam[2]);
}

extern "C" void kernel_launch(void* const* d_in, const int* in_sizes, int n_in,
                              void* d_out, int out_size, void* d_ws, size_t ws_size,
                              hipStream_t stream) {
    const float* f0 = (const float*)d_in[0];
    const float* f1 = (const float*)d_in[1];
    const float* f2 = (const float*)d_in[2];

    char* base = (char*)d_ws;
    unsigned short* ft = (unsigned short*)base;                   // 48 MB bf16 f^T x3
    unsigned short* Q  = (unsigned short*)base;                   // overlays ft (dead after syrk)
    unsigned short* P  = (unsigned short*)(base + 50331648);      // 6 MB bf16 M x3
    float* G32 = (float*)(base + 56623104);                       // 7.08 MB packed-upper fp32 (LIVE)
    float* trbuf = (float*)(base + 63700992);                     // 64 floats (zeroed)
    float* num = trbuf + 40;                                      // 3 floats (zeroed region)
    float* v = (float*)(base + 63701248);                         // 3*1024
    float* w = v + 3 * DIM;                                       // 3*1024

    // zero G32 (7077888 B) + trbuf/num (256 B) in one async memset
    hipMemsetAsync(G32, 0, 7078144, stream);

    dim3 gt(DIM / 64, NROW / 64, 3);
    tconv_k<<<gt, 256, 0, stream>>>(f0, f1, f2, ft);

    // G = ft ft' (K=8192), split-K x4, 2-phase pipelined, flat grid 432
    syrk_sk<<<432, 256, 0, stream>>>(ft, G32);
    // packed fp32 -> full bf16 P + trace (G32 preserved)
    convert_k<<<dim3(36, 1, 3), 256, 0, stream>>>(G32, trbuf, P);

    unsigned short* cur = P;
    unsigned short* nxt = Q;   // Q lives in the dead ft region
    for (int s = 0; s < NS; ++s) {
        sq_k<<<dim3(136, 1, 3), 256, 0, stream>>>(cur, trbuf + s * 3,
                                                  trbuf + (s + 1) * 3, nxt);
        unsigned short* t2 = cur; cur = nxt; nxt = t2;
    }
    // NS=5 (odd) => cur == Q

    dim3 b(256, 1, 1);
    dim3 gm(DIM / 4, 3, 1);
    mv_bf16<<<gm, b, 0, stream>>>(cur, nullptr, v);   // v = M*1
    mv_bf16<<<gm, b, 0, stream>>>(cur, v, w);         // w = M*v (polish)

    // num[m] = w' G32 w  (fp32 Gram, packed upper)
    ray_k<<<dim3(36, 3, 1), 256, 0, stream>>>(G32, w, num);
    final_k<<<1, 256, 0, stream>>>(num, w, (float*)d_out);
}

// Round 8
// 268.689 us; speedup vs baseline: 1.3823x; 1.3823x over previous
//
#include <hip/hip_runtime.h>

// BSPLoss: out = sig1(f1)^2 + 0.5*(sig1(f2)^2 + sig1(f3)^2), f: 8192x1024 fp32.
// sig1^2 = top eig of G = f'f. bf16 MFMA for G and 5 trace-normalized squarings
// (eigenvector only); final lambda = (w' G32 w)/|w|^2 with fp32-accumulated Gram.
// R20: R19 post-mortem -> direct-from-L2 sq fragments REGRESSED +19us/launch
// (scattered 16B/lane reads at 2KB stride + load->MFMA dependency chain =
// latency-bound; L2-resident != free). LDS staging earns its keep via
// coalescing + 16x reuse + 2-phase latency amortization. R20 = revert sq_k
// to R18's proven 2-phase ping-pong (276.3us state) + vectorize mv_bf16
// scalar bf16 loads to short8 (common-mistake #2; reorder-safe, Rayleigh
// quotient 1st-order insensitive). syrk unchanged (54.5us control).

#define DIM 1024
#define NROW 8192
#define MSZ (DIM*DIM)
#define NS 5

typedef __attribute__((ext_vector_type(8))) short short8;
typedef __attribute__((ext_vector_type(4))) float f32x4;

__device__ inline float bf2f(unsigned short u) {
    union { unsigned i; float f; } x; x.i = ((unsigned)u) << 16; return x.f;
}
__device__ inline unsigned short f2bf(float f) {
    union { float f; unsigned i; } x; x.f = f;
    unsigned r = x.i + 0x7FFFu + ((x.i >> 16) & 1u);
    return (unsigned short)(r >> 16);
}
__device__ inline void gload16(const void* g, void* l) {
    __builtin_amdgcn_global_load_lds(
        (const __attribute__((address_space(1))) unsigned int*)g,
        (__attribute__((address_space(3))) unsigned int*)l, 16, 0, 0);
}

// f fp32 [NROW][DIM] -> ft bf16 [DIM][NROW] (transposed), per matrix m.
__global__ __launch_bounds__(256)
void tconv_k(const float* __restrict__ f0, const float* __restrict__ f1,
             const float* __restrict__ f2, unsigned short* __restrict__ ft) {
    const int m = blockIdx.z;
    const float* f = (m == 0) ? f0 : (m == 1 ? f1 : f2);
    unsigned short* o = ft + (size_t)m * DIM * NROW;
    __shared__ float T[64][68];
    const int c0 = blockIdx.x * 64, r0 = blockIdx.y * 64;
    const int tid = threadIdx.x;
    const int cx = (tid & 15) * 4, ry = tid >> 4;
#pragma unroll
    for (int i = 0; i < 4; ++i) {
        int r = ry + i * 16;
        float4 v = *(const float4*)&f[(size_t)(r0 + r) * DIM + c0 + cx];
        T[cx + 0][r] = v.x;
        T[cx + 1][r] = v.y;
        T[cx + 2][r] = v.z;
        T[cx + 3][r] = v.w;
    }
    __syncthreads();
#pragma unroll
    for (int i = 0; i < 4; ++i) {
        int c = ry + i * 16;
        float4 g = *(const float4*)&T[c][cx];
        ushort4 u;
        u.x = f2bf(g.x); u.y = f2bf(g.y); u.z = f2bf(g.z); u.w = f2bf(g.w);
        *(ushort4*)&o[(size_t)(c0 + c) * NROW + r0 + cx] = u;
    }
}

// Split-K(4) symmetric SYRK, upper 128-tiles, fp32 atomicAdd into packed G.
// Flat grid 432: b = ky + 4*(tile + 36*m). XCD = b%8 = ky + 4*(tile&1).
// 2-phase software pipeline: ping-pong LDS (As0/Bs0, As1/Bs1), prefetch of
// K-step t+1 issued before compute of t, one __syncthreads per K-step.
__global__ __launch_bounds__(256)
void syrk_sk(const unsigned short* __restrict__ src, float* __restrict__ Gp) {
    const int b = blockIdx.x;
    const int ky = b & 3;
    const int q = b >> 2;            // 0..107
    const int m = q / 36;
    const int tile = q - m * 36;
    int idx = tile, ti = 0;
    while (idx >= 8 - ti) { idx -= 8 - ti; ++ti; }
    const int tj = ti + idx;
    const int i0 = ti * 128, j0 = tj * 128;
    const unsigned short* S = src + (size_t)m * DIM * NROW;
    float* G = Gp + ((size_t)m * 36 + tile) * 16384;
    const int k0b = ky << 11;        // Kc = 2048, 32 K-steps of 64

    __shared__ unsigned short As0[2 * 128 * 32];   // 16 KB each
    __shared__ unsigned short Bs0[2 * 128 * 32];
    __shared__ unsigned short As1[2 * 128 * 32];
    __shared__ unsigned short Bs1[2 * 128 * 32];

    const int tid = threadIdx.x, w = tid >> 6, lane = tid & 63;
    const int wi = w >> 1, wj = w & 1;

    f32x4 acc[4][4];
#pragma unroll
    for (int a = 0; a < 4; ++a)
#pragma unroll
        for (int c = 0; c < 4; ++c) acc[a][c] = (f32x4){0.f, 0.f, 0.f, 0.f};

    const int lr = lane >> 2;
    const int ksw = (((lane & 3) ^ ((lane >> 4) & 3)) * 8);
    const int fr = lane & 15;
    const int slot = (((lane >> 4) ^ ((fr >> 2) & 3)) * 8);

#define STAGE(AS, BS, KK)                                                     \
    _Pragma("unroll")                                                         \
    for (int h = 0; h < 2; ++h)                                               \
        _Pragma("unroll")                                                     \
        for (int p = 0; p < 2; ++p) {                                         \
            int rr = w * 32 + p * 16;                                         \
            gload16(S + (size_t)(i0 + rr + lr) * NROW + (KK) + h * 32 + ksw,  \
                    &(AS)[h * 4096 + rr * 32]);                               \
            gload16(S + (size_t)(j0 + rr + lr) * NROW + (KK) + h * 32 + ksw,  \
                    &(BS)[h * 4096 + rr * 32]);                               \
        }

#define COMPUTE(AS, BS)                                                       \
    _Pragma("unroll")                                                         \
    for (int h = 0; h < 2; ++h) {                                             \
        short8 af[4], bfv[4];                                                 \
        _Pragma("unroll")                                                     \
        for (int a = 0; a < 4; ++a)                                           \
            af[a] = *(const short8*)&(AS)[h * 4096 + (wi * 64 + a * 16 + fr) * 32 + slot]; \
        _Pragma("unroll")                                                     \
        for (int c = 0; c < 4; ++c)                                           \
            bfv[c] = *(const short8*)&(BS)[h * 4096 + (wj * 64 + c * 16 + fr) * 32 + slot]; \
        _Pragma("unroll")                                                     \
        for (int a = 0; a < 4; ++a)                                           \
            _Pragma("unroll")                                                 \
            for (int c = 0; c < 4; ++c)                                       \
                acc[a][c] = __builtin_amdgcn_mfma_f32_16x16x32_bf16(          \
                    af[a], bfv[c], acc[a][c], 0, 0, 0);                       \
    }

    // Prologue: stage K-step 0 into buf0.
    STAGE(As0, Bs0, k0b)
    __syncthreads();

    int k0 = k0b;
#pragma unroll 1
    for (int t = 0; t < 15; ++t) {
        STAGE(As1, Bs1, k0 + 64)      // prefetch odd step
        COMPUTE(As0, Bs0)             // compute even step (latency hides here)
        __syncthreads();              // drains prefetch, guards buf reuse
        STAGE(As0, Bs0, k0 + 128)     // prefetch next even step
        COMPUTE(As1, Bs1)
        __syncthreads();
        k0 += 128;
    }
    // Tail: steps 30 (staged in last loop iter) and 31.
    STAGE(As1, Bs1, k0 + 64)
    COMPUTE(As0, Bs0)
    __syncthreads();
    COMPUTE(As1, Bs1)

#undef STAGE
#undef COMPUTE

    const int qr = (lane >> 4) * 4, cn = lane & 15;
#pragma unroll
    for (int a = 0; a < 4; ++a)
#pragma unroll
        for (int c = 0; c < 4; ++c) {
            int cl = wj * 64 + c * 16 + cn;
#pragma unroll
            for (int reg = 0; reg < 4; ++reg) {
                int rl = wi * 64 + a * 16 + qr + reg;
                atomicAdd(&G[rl * 128 + cl], acc[a][c][reg]);
            }
        }
}

// Packed-upper fp32 G -> full bf16 matrix (mirror via swizzled LDS transpose),
// fused trace -> trout[m]. grid (36,1,3). G32 read-only (kept for ray_k).
__global__ __launch_bounds__(256)
void convert_k(const float* __restrict__ Gp, float* __restrict__ trout,
               unsigned short* __restrict__ dst) {
    const int m = blockIdx.z;
    int idx = blockIdx.x, ti = 0;
    while (idx >= 8 - ti) { idx -= 8 - ti; ++ti; }
    const int tj = ti + idx;
    const int i0 = ti * 128, j0 = tj * 128;
    const float* G = Gp + ((size_t)m * 36 + blockIdx.x) * 16384;
    unsigned short* D = dst + (size_t)m * MSZ;
    __shared__ unsigned short T[128][136];
    const int tid = threadIdx.x;
    const int cx = (tid & 31) * 4, ry = tid >> 5;
    float dtr = 0.f;
#pragma unroll 4
    for (int t = 0; t < 16; ++t) {
        int r = ry + t * 8;
        float4 g = *(const float4*)&G[r * 128 + cx];
        ushort4 o;
        o.x = f2bf(g.x); o.y = f2bf(g.y); o.z = f2bf(g.z); o.w = f2bf(g.w);
        *(ushort4*)&D[(size_t)(i0 + r) * DIM + j0 + cx] = o;
        int rs = r ^ (cx & 124);
        T[cx + 0][rs] = o.x; T[cx + 1][rs] = o.y;
        T[cx + 2][rs] = o.z; T[cx + 3][rs] = o.w;
        if (ti == tj) {
            int d = r - cx;
            if (d >= 0 && d < 4)
                dtr += (d == 0 ? g.x : d == 1 ? g.y : d == 2 ? g.z : g.w);
        }
    }
    if (ti == tj) atomicAdd(&trout[m], dtr);
    if (ti != tj) {
        __syncthreads();
#pragma unroll 4
        for (int t = 0; t < 16; ++t) {
            int p = ry + t * 8;
            int qs = cx ^ (p & 124);
            ushort4 o = *(const ushort4*)&T[p][qs];
            *(ushort4*)&D[(size_t)(j0 + p) * DIM + i0 + cx] = o;
        }
    }
}

// One trace-normalized squaring: dst = (src/tr)^2, symmetric 64-tiles, fused
// scale + mirror + trace. grid (136,1,3). BK=64, 2-phase ping-pong pipeline
// (R18-proven): prefetch K-step t+1 before compute of t, one sync per K-step.
__global__ __launch_bounds__(256)
void sq_k(const unsigned short* __restrict__ src, const float* __restrict__ trin,
          float* __restrict__ trout, unsigned short* __restrict__ dst) {
    const int m = blockIdx.z;
    const unsigned short* S = src + (size_t)m * MSZ;
    unsigned short* D = dst + (size_t)m * MSZ;
    int idx = blockIdx.x, ti = 0;
    while (idx >= 16 - ti) { idx -= 16 - ti; ++ti; }
    const int tj = ti + idx;
    const int i0 = ti * 64, j0 = tj * 64;
    float tv = trin[m];
    const float sc = 1.f / (tv * tv);

    __shared__ unsigned short As0[2 * 64 * 32];   // 8 KB each
    __shared__ unsigned short Bs0[2 * 64 * 32];
    __shared__ unsigned short As1[2 * 64 * 32];
    __shared__ unsigned short Bs1[2 * 64 * 32];
    __shared__ unsigned short Ts[64][68];

    const int tid = threadIdx.x, w = tid >> 6, lane = tid & 63;
    const int wi = w >> 1, wj = w & 1;
    f32x4 acc[2][2];
#pragma unroll
    for (int a = 0; a < 2; ++a)
#pragma unroll
        for (int b = 0; b < 2; ++b) acc[a][b] = (f32x4){0.f, 0.f, 0.f, 0.f};

    const int lr = lane >> 2;
    const int ksw = (((lane & 3) ^ ((lane >> 4) & 3)) * 8);
    const int fr = lane & 15;
    const int slot = (((lane >> 4) ^ ((fr >> 2) & 3)) * 8);

#define SQ_STAGE(AS, BS, KK)                                                  \
    _Pragma("unroll")                                                         \
    for (int h = 0; h < 2; ++h) {                                             \
        gload16(S + (size_t)(i0 + w * 16 + lr) * DIM + (KK) + h * 32 + ksw,   \
                &(AS)[h * 2048 + w * 16 * 32]);                               \
        gload16(S + (size_t)(j0 + w * 16 + lr) * DIM + (KK) + h * 32 + ksw,   \
                &(BS)[h * 2048 + w * 16 * 32]);                               \
    }

#define SQ_COMPUTE(AS, BS)                                                    \
    _Pragma("unroll")                                                         \
    for (int h = 0; h < 2; ++h) {                                             \
        short8 af[2], bfv[2];                                                 \
        _Pragma("unroll")                                                     \
        for (int a = 0; a < 2; ++a)                                           \
            af[a] = *(const short8*)&(AS)[h * 2048 + (wi * 32 + a * 16 + fr) * 32 + slot]; \
        _Pragma("unroll")                                                     \
        for (int c = 0; c < 2; ++c)                                           \
            bfv[c] = *(const short8*)&(BS)[h * 2048 + (wj * 32 + c * 16 + fr) * 32 + slot]; \
        _Pragma("unroll")                                                     \
        for (int a = 0; a < 2; ++a)                                           \
            _Pragma("unroll")                                                 \
            for (int c = 0; c < 2; ++c)                                       \
                acc[a][c] = __builtin_amdgcn_mfma_f32_16x16x32_bf16(          \
                    af[a], bfv[c], acc[a][c], 0, 0, 0);                       \
    }

    // Prologue: stage K-step 0 into buf0.
    SQ_STAGE(As0, Bs0, 0)
    __syncthreads();

    int k0 = 0;
#pragma unroll 1
    for (int t = 0; t < 7; ++t) {
        SQ_STAGE(As1, Bs1, k0 + 64)
        SQ_COMPUTE(As0, Bs0)
        __syncthreads();
        SQ_STAGE(As0, Bs0, k0 + 128)
        SQ_COMPUTE(As1, Bs1)
        __syncthreads();
        k0 += 128;
    }
    // Tail: steps 14 (k=896, staged in last loop iter) and 15 (k=960).
    SQ_STAGE(As1, Bs1, k0 + 64)
    SQ_COMPUTE(As0, Bs0)
    __syncthreads();
    SQ_COMPUTE(As1, Bs1)

#undef SQ_STAGE
#undef SQ_COMPUTE

    const int qr = (lane >> 4) * 4, cn = lane & 15;
#pragma unroll
    for (int a = 0; a < 2; ++a)
#pragma unroll
        for (int b = 0; b < 2; ++b) {
            int cl = wj * 32 + b * 16 + cn;
#pragma unroll
            for (int reg = 0; reg < 4; ++reg) {
                int rl = wi * 32 + a * 16 + qr + reg;
                unsigned short val = f2bf(acc[a][b][reg] * sc);
                D[(size_t)(i0 + rl) * DIM + j0 + cl] = val;
                Ts[cl][rl] = val;
            }
        }
    if (ti == tj && wi == wj) {
        int d = cn - qr;
        if (d >= 0 && d < 4)
            atomicAdd(&trout[m], (acc[0][0][d] + acc[1][1][d]) * sc);
    }
    if (ti != tj) {
        __syncthreads();
        const int cx = (tid & 15) * 4, ry = tid >> 4;
#pragma unroll
        for (int tq = 0; tq < 4; ++tq) {
            int p = ry + tq * 16;
            ushort4 o;
            o.x = Ts[p][cx + 0]; o.y = Ts[p][cx + 1];
            o.z = Ts[p][cx + 2]; o.w = Ts[p][cx + 3];
            *(ushort4*)&D[(size_t)(j0 + p) * DIM + i0 + cx] = o;
        }
    }
}

// vout[row] = sum_j M[row][j] * (vin ? vin[j] : 1), M bf16 symmetric.
// R20: short8 vectorized loads (16B/lane, 2 iters over DIM=1024).
__global__ __launch_bounds__(256)
void mv_bf16(const unsigned short* __restrict__ M, const float* __restrict__ vin,
             float* __restrict__ vout) {
    int m = blockIdx.y;
    const unsigned short* A = M + (size_t)m * MSZ;
    int wv = threadIdx.x >> 6, lane = threadIdx.x & 63;
    int row = blockIdx.x * 4 + wv;
    const unsigned short* a = A + (size_t)row * DIM;
    float s = 0.f;
    if (vin) {
        const float* v = vin + m * DIM;
#pragma unroll
        for (int jb = 0; jb < DIM; jb += 512) {
            int j = jb + lane * 8;
            short8 x = *(const short8*)&a[j];
#pragma unroll
            for (int u = 0; u < 8; ++u)
                s += bf2f((unsigned short)x[u]) * v[j + u];
        }
    } else {
#pragma unroll
        for (int jb = 0; jb < DIM; jb += 512) {
            int j = jb + lane * 8;
            short8 x = *(const short8*)&a[j];
#pragma unroll
            for (int u = 0; u < 8; ++u)
                s += bf2f((unsigned short)x[u]);
        }
    }
    for (int off = 32; off; off >>= 1) s += __shfl_down(s, off);
    if (lane == 0) vout[m * DIM + row] = s;
}

// num[m] += w_i' T w_j (x2 off-diag) over packed-upper fp32 tiles. grid (36,3).
__global__ __launch_bounds__(256)
void ray_k(const float* __restrict__ Gp, const float* __restrict__ wv,
           float* __restrict__ num) {
    const int m = blockIdx.y;
    int idx = blockIdx.x, ti = 0;
    while (idx >= 8 - ti) { idx -= 8 - ti; ++ti; }
    const int tj = ti + idx;
    const float* G = Gp + ((size_t)m * 36 + blockIdx.x) * 16384;
    const float* wi = wv + m * DIM + ti * 128;
    const float* wj = wv + m * DIM + tj * 128;
    const int tid = threadIdx.x;
    const int r = tid >> 1, c0 = (tid & 1) * 64;
    float inner = 0.f;
    const float4* g4 = (const float4*)&G[r * 128 + c0];
    const float4* w4 = (const float4*)&wj[c0];
#pragma unroll
    for (int t = 0; t < 16; ++t) {
        float4 g = g4[t], ww = w4[t];
        inner += g.x * ww.x + g.y * ww.y + g.z * ww.z + g.w * ww.w;
    }
    float s = wi[r] * inner;
    for (int off = 32; off; off >>= 1) s += __shfl_down(s, off);
    __shared__ float part[4];
    int lane = tid & 63, wx = tid >> 6;
    if (lane == 0) part[wx] = s;
    __syncthreads();
    if (tid == 0) {
        float tot = part[0] + part[1] + part[2] + part[3];
        if (ti != tj) tot *= 2.f;
        atomicAdd(&num[m], tot);
    }
}

// out = num0/|w0|^2 + 0.5*(num1/|w1|^2 + num2/|w2|^2)
__global__ __launch_bounds__(256)
void final_k(const float* __restrict__ num, const float* __restrict__ w,
             float* __restrict__ out) {
    __shared__ float red[256];
    int tid = threadIdx.x;
    float lam[3];
    for (int m = 0; m < 3; ++m) {
        float s = 0.f;
        for (int i = tid; i < DIM; i += 256) { float x = w[m * DIM + i]; s += x * x; }
        red[tid] = s; __syncthreads();
        for (int off = 128; off; off >>= 1) {
            if (tid < off) red[tid] += red[tid + off];
            __syncthreads();
        }
        lam[m] = num[m] / red[0]; __syncthreads();
    }
    if (tid == 0) out[0] = lam[0] + 0.5f * (lam[1] + lam[2]);
}

extern "C" void kernel_launch(void* const* d_in, const int* in_sizes, int n_in,
                              void* d_out, int out_size, void* d_ws, size_t ws_size,
                              hipStream_t stream) {
    const float* f0 = (const float*)d_in[0];
    const float* f1 = (const float*)d_in[1];
    const float* f2 = (const float*)d_in[2];

    char* base = (char*)d_ws;
    unsigned short* ft = (unsigned short*)base;                   // 48 MB bf16 f^T x3
    unsigned short* Q  = (unsigned short*)base;                   // overlays ft (dead after syrk)
    unsigned short* P  = (unsigned short*)(base + 50331648);      // 6 MB bf16 M x3
    float* G32 = (float*)(base + 56623104);                       // 7.08 MB packed-upper fp32 (LIVE)
    float* trbuf = (float*)(base + 63700992);                     // 64 floats (zeroed)
    float* num = trbuf + 40;                                      // 3 floats (zeroed region)
    float* v = (float*)(base + 63701248);                         // 3*1024
    float* w = v + 3 * DIM;                                       // 3*1024

    // zero G32 (7077888 B) + trbuf/num (256 B) in one async memset
    hipMemsetAsync(G32, 0, 7078144, stream);

    dim3 gt(DIM / 64, NROW / 64, 3);
    tconv_k<<<gt, 256, 0, stream>>>(f0, f1, f2, ft);

    // G = ft ft' (K=8192), split-K x4, 2-phase pipelined, flat grid 432
    syrk_sk<<<432, 256, 0, stream>>>(ft, G32);
    // packed fp32 -> full bf16 P + trace (G32 preserved)
    convert_k<<<dim3(36, 1, 3), 256, 0, stream>>>(G32, trbuf, P);

    unsigned short* cur = P;
    unsigned short* nxt = Q;   // Q lives in the dead ft region
    for (int s = 0; s < NS; ++s) {
        sq_k<<<dim3(136, 1, 3), 256, 0, stream>>>(cur, trbuf + s * 3,
                                                  trbuf + (s + 1) * 3, nxt);
        unsigned short* t2 = cur; cur = nxt; nxt = t2;
    }
    // NS=5 (odd) => cur == Q

    dim3 b(256, 1, 1);
    dim3 gm(DIM / 4, 3, 1);
    mv_bf16<<<gm, b, 0, stream>>>(cur, nullptr, v);   // v = M*1
    mv_bf16<<<gm, b, 0, stream>>>(cur, v, w);         // w = M*v (polish)

    // num[m] = w' G32 w  (fp32 Gram, packed upper)
    ray_k<<<dim3(36, 3, 1), 256, 0, stream>>>(G32, w, num);
    final_k<<<1, 256, 0, stream>>>(num, w, (float*)d_out);
}

// Round 9
// 266.269 us; speedup vs baseline: 1.3949x; 1.0091x over previous
//
#include <hip/hip_runtime.h>

// BSPLoss: out = sig1(f1)^2 + 0.5*(sig1(f2)^2 + sig1(f3)^2), f: 8192x1024 fp32.
// sig1^2 = top eig of G = f'f. bf16 MFMA for G and 5 trace-normalized squarings
// (eigenvector only); final lambda = (w' G32 w)/|w|^2 with fp32-accumulated Gram.
// R21: syrk deep pipeline. R20 state: syrk ~55-62 (noise band +-7), 65% stall,
// FETCH=input => HBM-latency (~900cyc) bound; 2-phase hides only ~300cyc
// (2 bufs = depth 1, __syncthreads drains vmcnt(0)). Fix per T3+T4 (m201
// recipe, counted vmcnt never 0 in main loop): 4 buffers at BK=32, prefetch
// 3 ahead, asm s_waitcnt vmcnt(12) + raw s_barrier pairs. MFMA sequence
// bit-identical (old h-half == one step) => absmax must stay 256. LDS 64KB
// (8x8KB), 2 blocks/CU. sq_k/tconv/mv unchanged (controls).

#define DIM 1024
#define NROW 8192
#define MSZ (DIM*DIM)
#define NS 5

typedef __attribute__((ext_vector_type(8))) short short8;
typedef __attribute__((ext_vector_type(4))) float f32x4;

__device__ inline float bf2f(unsigned short u) {
    union { unsigned i; float f; } x; x.i = ((unsigned)u) << 16; return x.f;
}
__device__ inline unsigned short f2bf(float f) {
    union { float f; unsigned i; } x; x.f = f;
    unsigned r = x.i + 0x7FFFu + ((x.i >> 16) & 1u);
    return (unsigned short)(r >> 16);
}
__device__ inline void gload16(const void* g, void* l) {
    __builtin_amdgcn_global_load_lds(
        (const __attribute__((address_space(1))) unsigned int*)g,
        (__attribute__((address_space(3))) unsigned int*)l, 16, 0, 0);
}

// f fp32 [NROW][DIM] -> ft bf16 [DIM][NROW] (transposed), per matrix m.
__global__ __launch_bounds__(256)
void tconv_k(const float* __restrict__ f0, const float* __restrict__ f1,
             const float* __restrict__ f2, unsigned short* __restrict__ ft) {
    const int m = blockIdx.z;
    const float* f = (m == 0) ? f0 : (m == 1 ? f1 : f2);
    unsigned short* o = ft + (size_t)m * DIM * NROW;
    __shared__ float T[64][68];
    const int c0 = blockIdx.x * 64, r0 = blockIdx.y * 64;
    const int tid = threadIdx.x;
    const int cx = (tid & 15) * 4, ry = tid >> 4;
#pragma unroll
    for (int i = 0; i < 4; ++i) {
        int r = ry + i * 16;
        float4 v = *(const float4*)&f[(size_t)(r0 + r) * DIM + c0 + cx];
        T[cx + 0][r] = v.x;
        T[cx + 1][r] = v.y;
        T[cx + 2][r] = v.z;
        T[cx + 3][r] = v.w;
    }
    __syncthreads();
#pragma unroll
    for (int i = 0; i < 4; ++i) {
        int c = ry + i * 16;
        float4 g = *(const float4*)&T[c][cx];
        ushort4 u;
        u.x = f2bf(g.x); u.y = f2bf(g.y); u.z = f2bf(g.z); u.w = f2bf(g.w);
        *(ushort4*)&o[(size_t)(c0 + c) * NROW + r0 + cx] = u;
    }
}

// Split-K(4) symmetric SYRK, upper 128-tiles, fp32 atomicAdd into packed G.
// Flat grid 432: b = ky + 4*(tile + 36*m). XCD = b%8 = ky + 4*(tile&1).
// R21: 4-buffer BK=32 pipeline, prefetch 3 ahead, counted vmcnt(12) + raw
// barriers (T3+T4). 64 K-steps of 32; stage L=4 gload16/thread/step.
__global__ __launch_bounds__(256)
void syrk_sk(const unsigned short* __restrict__ src, float* __restrict__ Gp) {
    const int b = blockIdx.x;
    const int ky = b & 3;
    const int q = b >> 2;            // 0..107
    const int m = q / 36;
    const int tile = q - m * 36;
    int idx = tile, ti = 0;
    while (idx >= 8 - ti) { idx -= 8 - ti; ++ti; }
    const int tj = ti + idx;
    const int i0 = ti * 128, j0 = tj * 128;
    const unsigned short* S = src + (size_t)m * DIM * NROW;
    float* G = Gp + ((size_t)m * 36 + tile) * 16384;
    const int k0b = ky << 11;        // Kc = 2048 = 64 steps of 32

    // 4-deep ring: 8 KB per operand-buffer, 64 KB total.
    __shared__ unsigned short As0[128 * 32], As1[128 * 32],
                              As2[128 * 32], As3[128 * 32];
    __shared__ unsigned short Bs0[128 * 32], Bs1[128 * 32],
                              Bs2[128 * 32], Bs3[128 * 32];

    const int tid = threadIdx.x, w = tid >> 6, lane = tid & 63;
    const int wi = w >> 1, wj = w & 1;

    f32x4 acc[4][4];
#pragma unroll
    for (int a = 0; a < 4; ++a)
#pragma unroll
        for (int c = 0; c < 4; ++c) acc[a][c] = (f32x4){0.f, 0.f, 0.f, 0.f};

    const int lr = lane >> 2;
    const int ksw = (((lane & 3) ^ ((lane >> 4) & 3)) * 8);
    const int fr = lane & 15;
    const int slot = (((lane >> 4) ^ ((fr >> 2) & 3)) * 8);

    // Stage one BK=32 step into ring slot I (4 gload16/thread: 2 A + 2 B).
#define STAGE(I, KK)                                                          \
    _Pragma("unroll")                                                         \
    for (int p = 0; p < 2; ++p) {                                             \
        int rr = w * 32 + p * 16;                                             \
        gload16(S + (size_t)(i0 + rr + lr) * NROW + (KK) + ksw,               \
                &As##I[rr * 32]);                                             \
        gload16(S + (size_t)(j0 + rr + lr) * NROW + (KK) + ksw,               \
                &Bs##I[rr * 32]);                                             \
    }

    // One BK=32 compute: 4+4 ds_read_b128, 16 MFMA (identical order to the
    // old per-h body => bit-identical accumulation).
#define COMPUTE(I)                                                            \
    {                                                                         \
        short8 af[4], bfv[4];                                                 \
        _Pragma("unroll")                                                     \
        for (int a = 0; a < 4; ++a)                                           \
            af[a] = *(const short8*)&As##I[(wi * 64 + a * 16 + fr) * 32 + slot]; \
        _Pragma("unroll")                                                     \
        for (int c = 0; c < 4; ++c)                                           \
            bfv[c] = *(const short8*)&Bs##I[(wj * 64 + c * 16 + fr) * 32 + slot]; \
        _Pragma("unroll")                                                     \
        for (int a = 0; a < 4; ++a)                                           \
            _Pragma("unroll")                                                 \
            for (int c = 0; c < 4; ++c)                                       \
                acc[a][c] = __builtin_amdgcn_mfma_f32_16x16x32_bf16(          \
                    af[a], bfv[c], acc[a][c], 0, 0, 0);                       \
    }

    // Round: stage step (t+3), wait until step t's loads landed (12 = loads
    // of t+1,t+2,t+3 still allowed in flight), barrier, compute t, barrier
    // (frees buffer SI's predecessor for the next round's STAGE).
#define ROUND(CI, SI, KK, VM)                                                 \
    STAGE(SI, KK)                                                             \
    asm volatile("s_waitcnt vmcnt(" #VM ")" ::: "memory");                    \
    __builtin_amdgcn_s_barrier();                                             \
    COMPUTE(CI)                                                               \
    __builtin_amdgcn_s_barrier();

#define ROUND_NOSTAGE(CI, VM)                                                 \
    asm volatile("s_waitcnt vmcnt(" #VM ")" ::: "memory");                    \
    __builtin_amdgcn_s_barrier();                                             \
    COMPUTE(CI)                                                               \
    __builtin_amdgcn_s_barrier();

    // Prologue: stage steps 0,1,2 (12 loads outstanding).
    STAGE(0, k0b)
    STAGE(1, k0b + 32)
    STAGE(2, k0b + 64)

    int kk = k0b;
#pragma unroll 1
    for (int tb = 0; tb < 14; ++tb) {        // steps 0..55, stages 3..58
        ROUND(0, 3, kk + 96, 12)
        ROUND(1, 0, kk + 128, 12)
        ROUND(2, 1, kk + 160, 12)
        ROUND(3, 2, kk + 192, 12)
        kk += 128;
    }
    // kk = k0b + 1792. Steps 56..60 (stages 59..63), then drain 61..63.
    ROUND(0, 3, kk + 96, 12)    // compute 56, stage s59
    ROUND(1, 0, kk + 128, 12)   // compute 57, stage s60
    ROUND(2, 1, kk + 160, 12)   // compute 58, stage s61
    ROUND(3, 2, kk + 192, 12)   // compute 59, stage s62
    ROUND(0, 3, kk + 224, 12)   // compute 60, stage s63
    ROUND_NOSTAGE(1, 8)         // compute 61
    ROUND_NOSTAGE(2, 4)         // compute 62
    ROUND_NOSTAGE(3, 0)         // compute 63

#undef STAGE
#undef COMPUTE
#undef ROUND
#undef ROUND_NOSTAGE

    const int qr = (lane >> 4) * 4, cn = lane & 15;
#pragma unroll
    for (int a = 0; a < 4; ++a)
#pragma unroll
        for (int c = 0; c < 4; ++c) {
            int cl = wj * 64 + c * 16 + cn;
#pragma unroll
            for (int reg = 0; reg < 4; ++reg) {
                int rl = wi * 64 + a * 16 + qr + reg;
                atomicAdd(&G[rl * 128 + cl], acc[a][c][reg]);
            }
        }
}

// Packed-upper fp32 G -> full bf16 matrix (mirror via swizzled LDS transpose),
// fused trace -> trout[m]. grid (36,1,3). G32 read-only (kept for ray_k).
__global__ __launch_bounds__(256)
void convert_k(const float* __restrict__ Gp, float* __restrict__ trout,
               unsigned short* __restrict__ dst) {
    const int m = blockIdx.z;
    int idx = blockIdx.x, ti = 0;
    while (idx >= 8 - ti) { idx -= 8 - ti; ++ti; }
    const int tj = ti + idx;
    const int i0 = ti * 128, j0 = tj * 128;
    const float* G = Gp + ((size_t)m * 36 + blockIdx.x) * 16384;
    unsigned short* D = dst + (size_t)m * MSZ;
    __shared__ unsigned short T[128][136];
    const int tid = threadIdx.x;
    const int cx = (tid & 31) * 4, ry = tid >> 5;
    float dtr = 0.f;
#pragma unroll 4
    for (int t = 0; t < 16; ++t) {
        int r = ry + t * 8;
        float4 g = *(const float4*)&G[r * 128 + cx];
        ushort4 o;
        o.x = f2bf(g.x); o.y = f2bf(g.y); o.z = f2bf(g.z); o.w = f2bf(g.w);
        *(ushort4*)&D[(size_t)(i0 + r) * DIM + j0 + cx] = o;
        int rs = r ^ (cx & 124);
        T[cx + 0][rs] = o.x; T[cx + 1][rs] = o.y;
        T[cx + 2][rs] = o.z; T[cx + 3][rs] = o.w;
        if (ti == tj) {
            int d = r - cx;
            if (d >= 0 && d < 4)
                dtr += (d == 0 ? g.x : d == 1 ? g.y : d == 2 ? g.z : g.w);
        }
    }
    if (ti == tj) atomicAdd(&trout[m], dtr);
    if (ti != tj) {
        __syncthreads();
#pragma unroll 4
        for (int t = 0; t < 16; ++t) {
            int p = ry + t * 8;
            int qs = cx ^ (p & 124);
            ushort4 o = *(const ushort4*)&T[p][qs];
            *(ushort4*)&D[(size_t)(j0 + p) * DIM + i0 + cx] = o;
        }
    }
}

// One trace-normalized squaring: dst = (src/tr)^2, symmetric 64-tiles, fused
// scale + mirror + trace. grid (136,1,3). BK=64, 2-phase ping-pong pipeline
// (R18-proven): prefetch K-step t+1 before compute of t, one sync per K-step.
__global__ __launch_bounds__(256)
void sq_k(const unsigned short* __restrict__ src, const float* __restrict__ trin,
          float* __restrict__ trout, unsigned short* __restrict__ dst) {
    const int m = blockIdx.z;
    const unsigned short* S = src + (size_t)m * MSZ;
    unsigned short* D = dst + (size_t)m * MSZ;
    int idx = blockIdx.x, ti = 0;
    while (idx >= 16 - ti) { idx -= 16 - ti; ++ti; }
    const int tj = ti + idx;
    const int i0 = ti * 64, j0 = tj * 64;
    float tv = trin[m];
    const float sc = 1.f / (tv * tv);

    __shared__ unsigned short As0[2 * 64 * 32];   // 8 KB each
    __shared__ unsigned short Bs0[2 * 64 * 32];
    __shared__ unsigned short As1[2 * 64 * 32];
    __shared__ unsigned short Bs1[2 * 64 * 32];
    __shared__ unsigned short Ts[64][68];

    const int tid = threadIdx.x, w = tid >> 6, lane = tid & 63;
    const int wi = w >> 1, wj = w & 1;
    f32x4 acc[2][2];
#pragma unroll
    for (int a = 0; a < 2; ++a)
#pragma unroll
        for (int b = 0; b < 2; ++b) acc[a][b] = (f32x4){0.f, 0.f, 0.f, 0.f};

    const int lr = lane >> 2;
    const int ksw = (((lane & 3) ^ ((lane >> 4) & 3)) * 8);
    const int fr = lane & 15;
    const int slot = (((lane >> 4) ^ ((fr >> 2) & 3)) * 8);

#define SQ_STAGE(AS, BS, KK)                                                  \
    _Pragma("unroll")                                                         \
    for (int h = 0; h < 2; ++h) {                                             \
        gload16(S + (size_t)(i0 + w * 16 + lr) * DIM + (KK) + h * 32 + ksw,   \
                &(AS)[h * 2048 + w * 16 * 32]);                               \
        gload16(S + (size_t)(j0 + w * 16 + lr) * DIM + (KK) + h * 32 + ksw,   \
                &(BS)[h * 2048 + w * 16 * 32]);                               \
    }

#define SQ_COMPUTE(AS, BS)                                                    \
    _Pragma("unroll")                                                         \
    for (int h = 0; h < 2; ++h) {                                             \
        short8 af[2], bfv[2];                                                 \
        _Pragma("unroll")                                                     \
        for (int a = 0; a < 2; ++a)                                           \
            af[a] = *(const short8*)&(AS)[h * 2048 + (wi * 32 + a * 16 + fr) * 32 + slot]; \
        _Pragma("unroll")                                                     \
        for (int c = 0; c < 2; ++c)                                           \
            bfv[c] = *(const short8*)&(BS)[h * 2048 + (wj * 32 + c * 16 + fr) * 32 + slot]; \
        _Pragma("unroll")                                                     \
        for (int a = 0; a < 2; ++a)                                           \
            _Pragma("unroll")                                                 \
            for (int c = 0; c < 2; ++c)                                       \
                acc[a][c] = __builtin_amdgcn_mfma_f32_16x16x32_bf16(          \
                    af[a], bfv[c], acc[a][c], 0, 0, 0);                       \
    }

    // Prologue: stage K-step 0 into buf0.
    SQ_STAGE(As0, Bs0, 0)
    __syncthreads();

    int k0 = 0;
#pragma unroll 1
    for (int t = 0; t < 7; ++t) {
        SQ_STAGE(As1, Bs1, k0 + 64)
        SQ_COMPUTE(As0, Bs0)
        __syncthreads();
        SQ_STAGE(As0, Bs0, k0 + 128)
        SQ_COMPUTE(As1, Bs1)
        __syncthreads();
        k0 += 128;
    }
    // Tail: steps 14 (k=896, staged in last loop iter) and 15 (k=960).
    SQ_STAGE(As1, Bs1, k0 + 64)
    SQ_COMPUTE(As0, Bs0)
    __syncthreads();
    SQ_COMPUTE(As1, Bs1)

#undef SQ_STAGE
#undef SQ_COMPUTE

    const int qr = (lane >> 4) * 4, cn = lane & 15;
#pragma unroll
    for (int a = 0; a < 2; ++a)
#pragma unroll
        for (int b = 0; b < 2; ++b) {
            int cl = wj * 32 + b * 16 + cn;
#pragma unroll
            for (int reg = 0; reg < 4; ++reg) {
                int rl = wi * 32 + a * 16 + qr + reg;
                unsigned short val = f2bf(acc[a][b][reg] * sc);
                D[(size_t)(i0 + rl) * DIM + j0 + cl] = val;
                Ts[cl][rl] = val;
            }
        }
    if (ti == tj && wi == wj) {
        int d = cn - qr;
        if (d >= 0 && d < 4)
            atomicAdd(&trout[m], (acc[0][0][d] + acc[1][1][d]) * sc);
    }
    if (ti != tj) {
        __syncthreads();
        const int cx = (tid & 15) * 4, ry = tid >> 4;
#pragma unroll
        for (int tq = 0; tq < 4; ++tq) {
            int p = ry + tq * 16;
            ushort4 o;
            o.x = Ts[p][cx + 0]; o.y = Ts[p][cx + 1];
            o.z = Ts[p][cx + 2]; o.w = Ts[p][cx + 3];
            *(ushort4*)&D[(size_t)(j0 + p) * DIM + i0 + cx] = o;
        }
    }
}

// vout[row] = sum_j M[row][j] * (vin ? vin[j] : 1), M bf16 symmetric.
// R20: short8 vectorized loads (16B/lane, 2 iters over DIM=1024).
__global__ __launch_bounds__(256)
void mv_bf16(const unsigned short* __restrict__ M, const float* __restrict__ vin,
             float* __restrict__ vout) {
    int m = blockIdx.y;
    const unsigned short* A = M + (size_t)m * MSZ;
    int wv = threadIdx.x >> 6, lane = threadIdx.x & 63;
    int row = blockIdx.x * 4 + wv;
    const unsigned short* a = A + (size_t)row * DIM;
    float s = 0.f;
    if (vin) {
        const float* v = vin + m * DIM;
#pragma unroll
        for (int jb = 0; jb < DIM; jb += 512) {
            int j = jb + lane * 8;
            short8 x = *(const short8*)&a[j];
#pragma unroll
            for (int u = 0; u < 8; ++u)
                s += bf2f((unsigned short)x[u]) * v[j + u];
        }
    } else {
#pragma unroll
        for (int jb = 0; jb < DIM; jb += 512) {
            int j = jb + lane * 8;
            short8 x = *(const short8*)&a[j];
#pragma unroll
            for (int u = 0; u < 8; ++u)
                s += bf2f((unsigned short)x[u]);
        }
    }
    for (int off = 32; off; off >>= 1) s += __shfl_down(s, off);
    if (lane == 0) vout[m * DIM + row] = s;
}

// num[m] += w_i' T w_j (x2 off-diag) over packed-upper fp32 tiles. grid (36,3).
__global__ __launch_bounds__(256)
void ray_k(const float* __restrict__ Gp, const float* __restrict__ wv,
           float* __restrict__ num) {
    const int m = blockIdx.y;
    int idx = blockIdx.x, ti = 0;
    while (idx >= 8 - ti) { idx -= 8 - ti; ++ti; }
    const int tj = ti + idx;
    const float* G = Gp + ((size_t)m * 36 + blockIdx.x) * 16384;
    const float* wi = wv + m * DIM + ti * 128;
    const float* wj = wv + m * DIM + tj * 128;
    const int tid = threadIdx.x;
    const int r = tid >> 1, c0 = (tid & 1) * 64;
    float inner = 0.f;
    const float4* g4 = (const float4*)&G[r * 128 + c0];
    const float4* w4 = (const float4*)&wj[c0];
#pragma unroll
    for (int t = 0; t < 16; ++t) {
        float4 g = g4[t], ww = w4[t];
        inner += g.x * ww.x + g.y * ww.y + g.z * ww.z + g.w * ww.w;
    }
    float s = wi[r] * inner;
    for (int off = 32; off; off >>= 1) s += __shfl_down(s, off);
    __shared__ float part[4];
    int lane = tid & 63, wx = tid >> 6;
    if (lane == 0) part[wx] = s;
    __syncthreads();
    if (tid == 0) {
        float tot = part[0] + part[1] + part[2] + part[3];
        if (ti != tj) tot *= 2.f;
        atomicAdd(&num[m], tot);
    }
}

// out = num0/|w0|^2 + 0.5*(num1/|w1|^2 + num2/|w2|^2)
__global__ __launch_bounds__(256)
void final_k(const float* __restrict__ num, const float* __restrict__ w,
             float* __restrict__ out) {
    __shared__ float red[256];
    int tid = threadIdx.x;
    float lam[3];
    for (int m = 0; m < 3; ++m) {
        float s = 0.f;
        for (int i = tid; i < DIM; i += 256) { float x = w[m * DIM + i]; s += x * x; }
        red[tid] = s; __syncthreads();
        for (int off = 128; off; off >>= 1) {
            if (tid < off) red[tid] += red[tid + off];
            __syncthreads();
        }
        lam[m] = num[m] / red[0]; __syncthreads();
    }
    if (tid == 0) out[0] = lam[0] + 0.5f * (lam[1] + lam[2]);
}

extern "C" void kernel_launch(void* const* d_in, const int* in_sizes, int n_in,
                              void* d_out, int out_size, void* d_ws, size_t ws_size,
                              hipStream_t stream) {
    const float* f0 = (const float*)d_in[0];
    const float* f1 = (const float*)d_in[1];
    const float* f2 = (const float*)d_in[2];

    char* base = (char*)d_ws;
    unsigned short* ft = (unsigned short*)base;                   // 48 MB bf16 f^T x3
    unsigned short* Q  = (unsigned short*)base;                   // overlays ft (dead after syrk)
    unsigned short* P  = (unsigned short*)(base + 50331648);      // 6 MB bf16 M x3
    float* G32 = (float*)(base + 56623104);                       // 7.08 MB packed-upper fp32 (LIVE)
    float* trbuf = (float*)(base + 63700992);                     // 64 floats (zeroed)
    float* num = trbuf + 40;                                      // 3 floats (zeroed region)
    float* v = (float*)(base + 63701248);                         // 3*1024
    float* w = v + 3 * DIM;                                       // 3*1024

    // zero G32 (7077888 B) + trbuf/num (256 B) in one async memset
    hipMemsetAsync(G32, 0, 7078144, stream);

    dim3 gt(DIM / 64, NROW / 64, 3);
    tconv_k<<<gt, 256, 0, stream>>>(f0, f1, f2, ft);

    // G = ft ft' (K=8192), split-K x4, 4-deep counted-vmcnt pipeline, grid 432
    syrk_sk<<<432, 256, 0, stream>>>(ft, G32);
    // packed fp32 -> full bf16 P + trace (G32 preserved)
    convert_k<<<dim3(36, 1, 3), 256, 0, stream>>>(G32, trbuf, P);

    unsigned short* cur = P;
    unsigned short* nxt = Q;   // Q lives in the dead ft region
    for (int s = 0; s < NS; ++s) {
        sq_k<<<dim3(136, 1, 3), 256, 0, stream>>>(cur, trbuf + s * 3,
                                                  trbuf + (s + 1) * 3, nxt);
        unsigned short* t2 = cur; cur = nxt; nxt = t2;
    }
    // NS=5 (odd) => cur == Q

    dim3 b(256, 1, 1);
    dim3 gm(DIM / 4, 3, 1);
    mv_bf16<<<gm, b, 0, stream>>>(cur, nullptr, v);   // v = M*1
    mv_bf16<<<gm, b, 0, stream>>>(cur, v, w);         // w = M*v (polish)

    // num[m] = w' G32 w  (fp32 Gram, packed upper)
    ray_k<<<dim3(36, 3, 1), 256, 0, stream>>>(G32, w, num);
    final_k<<<1, 256, 0, stream>>>(num, w, (float*)d_out);
}